// Round 2
// baseline (95.939 us; speedup 1.0000x reference)
//
#include <hip/hip_runtime.h>
#include <math.h>

#define N 4096
#define FEPS 1e-7f
#define BLK 256
#define JT 64           // grid = 16*64 = 1024 blocks = 4 blocks/CU = 4 waves/SIMD
#define CH 64           // j-chunk == wave size: one j-record per lane
#define N6 (N * 6)

// d_ws layout: part[jt][i*6+k] : JT*N*6 floats = 6.29 MB. No feature table.

// Per-box record (12 floats): 0:conf 1:x1 2:y1 3:x2 4:y2 5:(x1+x2)/2
// 6:(y1+y2)/2 7:w 8:h 9:area+eps/2 10:(2/pi)*atan(w/(h+eps)) 11:conf*sqrt(log2e)
// Folds: K=4/pi^2 into atan, rho2's /4 into half-coords, union-eps split
// across the two records, log2(e) for v_exp_f32 (2^x) into conf.
__device__ __forceinline__ void box_record(const float* __restrict__ x, int i, float* rec) {
    float cf = x[i * 5 + 0], x1 = x[i * 5 + 1], y1 = x[i * 5 + 2];
    float x2 = x[i * 5 + 3], y2 = x[i * 5 + 4];
    float w = x2 - x1, h = y2 - y1;
    rec[0] = cf; rec[1] = x1; rec[2] = y1; rec[3] = x2; rec[4] = y2;
    rec[5] = (x1 + x2) * 0.5f; rec[6] = (y1 + y2) * 0.5f; rec[7] = w; rec[8] = h;
    rec[9] = w * h + 0.5f * FEPS;
    rec[10] = 0.6366197723675814f * atanf(w / (h + FEPS));
    rec[11] = cf * 1.2011224087864498f;
}

// Broadcast lane jj's value to all lanes. jj is a uniform loop counter ->
// SGPR lane-select -> v_readlane_b32 (VALU, per-SIMD pipe). This is the
// r1->r2 change: r0 (12x ds_read broadcast/iter, shared per-CU LDS pipe)
// and r1 (wave-uniform global loads, VMEM latency) both left the main
// kernel at ~33us vs its ~13us VALU floor (r0/r1 measured neutral).
// Register-resident j-records + readlane remove ALL in-loop memory.
__device__ __forceinline__ float rdlane(float v, int l) {
    return __int_as_float(__builtin_amdgcn_readlane(__float_as_int(v), l));
}

// Row-per-lane, register-broadcast j-loop. Block (gb, jt): lane owns row
// i = gb*256+tid; the wave's 64 lanes each hold ONE j-record of chunk
// [jt*64, jt*64+64) in 12 VGPRs; inner loop broadcasts them via readlane.
// No LDS, no __syncthreads, no in-loop loads.
//
// Fused rcp (kept from r1, absmax 0.0): rho2/c2 + v^2/den ==
// (rho2*den + v^2*c2)/(c2*den); diagonal (iou=1,v=0) -> num=0 -> ciou=iou.
// iou clamped to 1.0: fast-rcp 1-ulp overshoot otherwise zeroes den on
// diagonal pairs -> 0*inf = NaN (measured in the earlier session).
// NOTE (prior session, measured): no 2nd __launch_bounds__ arg — (256,4)
// forced VGPR=64 and spilled ~90 MB/dispatch to scratch.
__global__ __launch_bounds__(BLK) void ciou_attn_kernel(
        const float* __restrict__ x,
        float* __restrict__ part) {
    const int tid = threadIdx.x;
    const int lane = tid & 63;
    const int gb = blockIdx.x / JT;
    const int jt = blockIdx.x % JT;
    const int i = gb * BLK + tid;

    // Per-lane row record (one-time, ~1 atanf).
    float R[12];
    box_record(x, i, R);
    const float rx1 = R[1], ry1 = R[2], rx2 = R[3], ry2 = R[4];
    const float rhx = R[5], rhy = R[6], rw = R[7], rh = R[8];
    const float rareps = R[9], rat = R[10], rcf2 = R[11];

    // This lane's j-record (one-time): j = jt*64 + lane, same across the
    // block's 4 waves (each wave holds the full chunk in its own registers).
    float J[12];
    box_record(x, jt * CH + lane, J);

    float sum = 0.f, a0 = 0.f, a1 = 0.f, a2 = 0.f, a3 = 0.f, a4 = 0.f;
    const float ONEP = 1.f + FEPS;

#pragma unroll 4
    for (int jj = 0; jj < CH; jj++) {
        float jcf = rdlane(J[0], jj);
        float jx1 = rdlane(J[1], jj);
        float jy1 = rdlane(J[2], jj);
        float jx2 = rdlane(J[3], jj);
        float jy2 = rdlane(J[4], jj);
        float jhx = rdlane(J[5], jj);
        float jhy = rdlane(J[6], jj);
        float jw  = rdlane(J[7], jj);
        float jh  = rdlane(J[8], jj);
        float jareps = rdlane(J[9], jj);
        float jat  = rdlane(J[10], jj);
        float jcf2 = rdlane(J[11], jj);

        float iwr = fminf(rx2, jx2) - fmaxf(rx1, jx1);
        float ihr = fminf(ry2, jy2) - fmaxf(ry1, jy1);
        float iw = fmaxf(iwr, 0.f);
        float ih = fmaxf(ihr, 0.f);
        float inter = iw * ih;
        float uni = (rareps + jareps) - inter;
        float iou = fminf(inter * __builtin_amdgcn_rcpf(uni), 1.0f);
        float cw = (rw + jw) - iwr;              // enclosing box identity
        float chh = (rh + jh) - ihr;
        float c2 = fmaf(cw, cw, fmaf(chh, chh, FEPS));
        float dx = jhx - rhx;
        float dy = jhy - rhy;
        float rho2 = fmaf(dx, dx, dy * dy);      // /4 pre-folded
        float da = jat - rat;                    // K pre-folded
        float v = da * da;
        float den = (v - iou) + ONEP;
        float num = fmaf(v * v, c2, rho2 * den); // rho2/c2 + v^2/den, fused
        float ciou = fmaf(-num, __builtin_amdgcn_rcpf(c2 * den), iou);
        float e = __builtin_amdgcn_exp2f(ciou * (rcf2 * jcf2));  // e^s
        sum += e;
        a0 = fmaf(e, jcf, a0);
        a1 = fmaf(e, jx1, a1);
        a2 = fmaf(e, jy1, a2);
        a3 = fmaf(e, jx2, a3);
        a4 = fmaf(e, jy2, a4);
    }

    float* p = part + (size_t)jt * N6 + (size_t)i * 6;
    p[0] = sum; p[1] = a0; p[2] = a1; p[3] = a2; p[4] = a3; p[5] = a4;
}

// One thread per output element (i,c): sum JT partials, softmax-divide, sigmoid.
__global__ void epilogue_kernel(const float* __restrict__ x,
                                const float* __restrict__ gamma,
                                const float* __restrict__ part,
                                float* __restrict__ out) {
    int idx = blockIdx.x * blockDim.x + threadIdx.x;
    if (idx >= N * 5) return;
    int i = idx / 5, c = idx % 5;
    float se = 0.f, a = 0.f;
    const float* p = part + (size_t)i * 6;
#pragma unroll 8
    for (int jt = 0; jt < JT; jt++) {
        se += p[jt * (size_t)N6 + 0];
        a  += p[jt * (size_t)N6 + 1 + c];
    }
    float xp = x[idx] * gamma[0] + a / se;
    out[idx] = 1.f / (1.f + expf(-xp));
}

extern "C" void kernel_launch(void* const* d_in, const int* in_sizes, int n_in,
                              void* d_out, int out_size, void* d_ws, size_t ws_size,
                              hipStream_t stream) {
    const float* x = (const float*)d_in[0];
    const float* gamma = (const float*)d_in[1];
    float* out = (float*)d_out;
    float* part = (float*)d_ws;  // JT*N*6 floats = 6.29 MB

    ciou_attn_kernel<<<(N / BLK) * JT, BLK, 0, stream>>>(x, part);
    epilogue_kernel<<<(N * 5 + 255) / 256, 256, 0, stream>>>(x, gamma, part, out);
}

// Round 3
// 93.948 us; speedup vs baseline: 1.0212x; 1.0212x over previous
//
#include <hip/hip_runtime.h>
#include <math.h>

#define N 4096
#define FEPS 1e-7f
#define HEPS 5e-8f      // FEPS/2, split across the two records of a pair
#define BLK 256
#define ROWS 4          // rows per thread: one j-broadcast feeds 4 pair-computations
#define JT 128          // j-chunks
#define CH (N / JT)     // 32 j's staged in LDS per block
#define JSTR 8          // padded record stride: coords 16B-aligned -> ds_read_b128
#define N6 (N * 6)
#define KATAN 0.6366197723675814f   // 2/pi (folds 4/pi^2 into atan)
#define SQL2E 1.2011224087864498f   // sqrt(log2 e), folds exp->exp2 into conf

// d_ws: part[jt][i*6+k] : JT*N*6 floats = 12.6 MB.

// r2->r3 (measured r0=83.9 LDS-broadcast, r1=86.2 uniform-VMEM, r2=95.9
// readlane): broadcast cost scales waves*iters*fields on EVERY pipe tried;
// main kernel stuck ~35us vs ~11us VALU floor. Fix = amortize, not relocate:
//   ROWS=4 rows/thread  -> 4 pair-computations per broadcast
//   record 12->6 fields -> derived fields (w,h,hx,hy,area,cf2) computed once
//                          per iter in VALU, shared across the 4 rows
//   JSTR=8 padding      -> coords 16B-aligned: 1 ds_read_b128 + 1 ds_read_b64
//                          per iter (was 12x ds_read_b32)
// LDS pipe: ~30us/CU -> ~2us/CU. Expected main kernel ~13us (VALU-bound).
//
// Kept from earlier rounds (all measured):
//  - fused rcp: rho2/c2 + v^2/den == (rho2*den + v^2*c2)/(c2*den);
//    diagonal (iou=1,v=0) -> num=0 -> ciou=iou exactly.
//  - iou clamped to 1.0: fast-rcp 1-ulp overshoot otherwise zeroes den on
//    diagonal pairs -> 0*inf = NaN.
//  - NO 2nd __launch_bounds__ arg: (256,4) forced VGPR=64, ~90MB spills.
__global__ __launch_bounds__(BLK) void ciou_attn_kernel(
        const float* __restrict__ x,
        float* __restrict__ part) {
    __shared__ float jrec[CH * JSTR];   // 1 KB
    const int tid = threadIdx.x;
    const int gb = blockIdx.x / JT;
    const int jt = blockIdx.x % JT;

    // Stage j-chunk (first CH threads): raw coords + conf + pre-folded atan.
    if (tid < CH) {
        int j = jt * CH + tid;
        float cf = x[j * 5 + 0], jx1 = x[j * 5 + 1], jy1 = x[j * 5 + 2];
        float jx2 = x[j * 5 + 3], jy2 = x[j * 5 + 4];
        float w = jx2 - jx1, h = jy2 - jy1;
        float at = KATAN * atanf(w / (h + FEPS));
        float4* v = (float4*)&jrec[tid * JSTR];
        v[0] = make_float4(jx1, jy1, jx2, jy2);
        v[1] = make_float4(cf, at, 0.f, 0.f);
    }

    // Per-lane row records for 4 rows (strided BLK apart -> coalesced).
    float rx1[ROWS], ry1[ROWS], rx2[ROWS], ry2[ROWS], rhx[ROWS], rhy[ROWS];
    float rw[ROWS], rh[ROWS], rareps[ROWS], rat[ROWS], rcf2[ROWS];
#pragma unroll
    for (int r = 0; r < ROWS; r++) {
        int i = gb * (BLK * ROWS) + r * BLK + tid;
        float cf = x[i * 5 + 0];
        rx1[r] = x[i * 5 + 1]; ry1[r] = x[i * 5 + 2];
        rx2[r] = x[i * 5 + 3]; ry2[r] = x[i * 5 + 4];
        rw[r] = rx2[r] - rx1[r]; rh[r] = ry2[r] - ry1[r];
        rhx[r] = (rx1[r] + rx2[r]) * 0.5f; rhy[r] = (ry1[r] + ry2[r]) * 0.5f;
        rareps[r] = fmaf(rw[r], rh[r], HEPS);
        rat[r] = KATAN * atanf(rw[r] / (rh[r] + FEPS));
        rcf2[r] = cf * SQL2E;
    }

    __syncthreads();

    float acc[ROWS][6] = {};   // [r][0]=sum, [r][1..5]=a0..a4; static idx only
    const float ONEP = 1.f + FEPS;

#pragma unroll 2
    for (int jj = 0; jj < CH; jj++) {
        const float4 b = *(const float4*)&jrec[jj * JSTR];       // ds_read_b128
        const float jcf = jrec[jj * JSTR + 4];                   // ds_read_b64
        const float jat = jrec[jj * JSTR + 5];
        // Shared j-derivations (once per iter, feeds all 4 rows).
        const float jw = b.z - b.x, jh = b.w - b.y;
        const float jhx = (b.x + b.z) * 0.5f, jhy = (b.y + b.w) * 0.5f;
        const float jareps = fmaf(jw, jh, HEPS);
        const float jcf2 = jcf * SQL2E;

#pragma unroll
        for (int r = 0; r < ROWS; r++) {
            float iwr = fminf(rx2[r], b.z) - fmaxf(rx1[r], b.x);
            float ihr = fminf(ry2[r], b.w) - fmaxf(ry1[r], b.y);
            float iw = fmaxf(iwr, 0.f);
            float ih = fmaxf(ihr, 0.f);
            float inter = iw * ih;
            float uni = (rareps[r] + jareps) - inter;
            float iou = fminf(inter * __builtin_amdgcn_rcpf(uni), 1.0f);
            float cw = (rw[r] + jw) - iwr;       // enclosing box identity
            float chh = (rh[r] + jh) - ihr;
            float c2 = fmaf(cw, cw, fmaf(chh, chh, FEPS));
            float dx = jhx - rhx[r];
            float dy = jhy - rhy[r];
            float rho2 = fmaf(dx, dx, dy * dy);  // /4 pre-folded
            float da = jat - rat[r];             // K pre-folded
            float v = da * da;
            float den = (v - iou) + ONEP;
            float num = fmaf(v * v, c2, rho2 * den);
            float ciou = fmaf(-num, __builtin_amdgcn_rcpf(c2 * den), iou);
            float e = __builtin_amdgcn_exp2f(ciou * (rcf2[r] * jcf2));
            acc[r][0] += e;
            acc[r][1] = fmaf(e, jcf, acc[r][1]);
            acc[r][2] = fmaf(e, b.x, acc[r][2]);
            acc[r][3] = fmaf(e, b.y, acc[r][3]);
            acc[r][4] = fmaf(e, b.z, acc[r][4]);
            acc[r][5] = fmaf(e, b.w, acc[r][5]);
        }
    }

#pragma unroll
    for (int r = 0; r < ROWS; r++) {
        int i = gb * (BLK * ROWS) + r * BLK + tid;
        float* p = part + (size_t)jt * N6 + (size_t)i * 6;
        p[0] = acc[r][0]; p[1] = acc[r][1]; p[2] = acc[r][2];
        p[3] = acc[r][3]; p[4] = acc[r][4]; p[5] = acc[r][5];
    }
}

// One thread per output element (i,c): sum JT partials, softmax-divide, sigmoid.
__global__ void epilogue_kernel(const float* __restrict__ x,
                                const float* __restrict__ gamma,
                                const float* __restrict__ part,
                                float* __restrict__ out) {
    int idx = blockIdx.x * blockDim.x + threadIdx.x;
    if (idx >= N * 5) return;
    int i = idx / 5, c = idx % 5;
    float se = 0.f, a = 0.f;
    const float* p = part + (size_t)i * 6;
#pragma unroll 16
    for (int jt = 0; jt < JT; jt++) {
        se += p[jt * (size_t)N6 + 0];
        a  += p[jt * (size_t)N6 + 1 + c];
    }
    float xp = x[idx] * gamma[0] + a / se;
    out[idx] = 1.f / (1.f + expf(-xp));
}

extern "C" void kernel_launch(void* const* d_in, const int* in_sizes, int n_in,
                              void* d_out, int out_size, void* d_ws, size_t ws_size,
                              hipStream_t stream) {
    const float* x = (const float*)d_in[0];
    const float* gamma = (const float*)d_in[1];
    float* out = (float*)d_out;
    float* part = (float*)d_ws;  // JT*N*6 floats = 12.6 MB

    ciou_attn_kernel<<<(N / (BLK * ROWS)) * JT, BLK, 0, stream>>>(x, part);
    epilogue_kernel<<<(N * 5 + 255) / 256, 256, 0, stream>>>(x, gamma, part, out);
}

// Round 4
// 83.702 us; speedup vs baseline: 1.1462x; 1.1224x over previous
//
#include <hip/hip_runtime.h>
#include <math.h>

#define N 4096
#define FEPS 1e-7f
#define HEPS 5e-8f      // FEPS/2, split across the two records of a pair
#define BLK 256
#define JT 64           // grid = 16*64 = 1024 blocks (r0 geometry, best measured)
#define CH (N / JT)     // 64 j's staged in LDS per block
#define N6 (N * 6)
#define KATAN 0.6366197723675814f   // 2/pi (folds 4/pi^2 into atan)
#define SQL2E 1.2011224087864498f   // sqrt(log2 e), folds exp->exp2 into conf

// d_ws: part[jt][i*6+k] : JT*N*6 floats = 6.29 MB.

// History (all measured): r0=83.9 (12x ds_read_b32/iter), r1=86.2 (uniform
// VMEM), r2=95.9 (readlane), r3=93.9 (4-row amortize, 24x less LDS traffic).
// Broadcast relocation/amortization never helped -> main kernel (~35us vs
// ~12us issue floor) is NOT fetch-bandwidth-bound. r2's +12 ops/iter cost
// +12.7us -> issue/latency exposed per iteration. r4 theory: hipcc does not
// software-pipeline the j-fetch across iterations (fetch at top of iter,
// used immediately -> ~120cy lgkmcnt exposed per iter) and the 3-trans
// dependent chain (rcp->den->rcp->ciou->exp2) serializes on top.
// Fixes, SAME r0 geometry:
//  1. register double-buffer: prefetch j-record jj+1 (3x ds_read_b128)
//     before computing with jj -> waitcnt lands after ~100cy of math.
//  2. common-denominator CIoU: one rcp instead of two, numerator computes
//     in parallel with the rcp:
//       den = v - iou + 1 + eps;  P = den*uni = (v+1+eps)*uni - inter > 0
//       ciou = [P*(inter*c2 - rho2*uni) - v^2*uni^2*c2] / (uni*c2*P)
//     P clamped >=1e-12 (fp cancellation on diagonal; P cancels exactly in
//     the ratio there -> ciou = A/(A+eps) = reference value).
//     Trans/pair 3 -> 2; chain ~90cy -> ~50cy.
// NOTE (prior session, measured): no 2nd __launch_bounds__ arg — (256,4)
// forced VGPR=64 and spilled ~90 MB/dispatch to scratch.
__global__ __launch_bounds__(BLK) void ciou_attn_kernel(
        const float* __restrict__ x,
        float* __restrict__ part) {
    // 12-float record per j, three aligned float4s:
    // A=[x1,y1,x2,y2]  B=[hx,hy,w,h]  C=[area+eps/2, atan_folded, cf2, cf]
    __shared__ float4 jrec[CH * 3];   // 3 KB
    const int tid = threadIdx.x;
    const int gb = blockIdx.x / JT;
    const int jt = blockIdx.x % JT;
    const int i = gb * BLK + tid;

    if (tid < CH) {
        int j = jt * CH + tid;
        float cf = x[j * 5 + 0], jx1 = x[j * 5 + 1], jy1 = x[j * 5 + 2];
        float jx2 = x[j * 5 + 3], jy2 = x[j * 5 + 4];
        float w = jx2 - jx1, h = jy2 - jy1;
        jrec[tid * 3 + 0] = make_float4(jx1, jy1, jx2, jy2);
        jrec[tid * 3 + 1] = make_float4((jx1 + jx2) * 0.5f, (jy1 + jy2) * 0.5f, w, h);
        jrec[tid * 3 + 2] = make_float4(fmaf(w, h, HEPS),
                                        KATAN * atanf(w / (h + FEPS)),
                                        cf * SQL2E, cf);
    }

    // Per-lane row record.
    {
    }
    float cfr = x[i * 5 + 0];
    const float rx1 = x[i * 5 + 1], ry1 = x[i * 5 + 2];
    const float rx2 = x[i * 5 + 3], ry2 = x[i * 5 + 4];
    const float rw = rx2 - rx1, rh = ry2 - ry1;
    const float rhx = (rx1 + rx2) * 0.5f, rhy = (ry1 + ry2) * 0.5f;
    const float rareps = fmaf(rw, rh, HEPS);
    const float rat = KATAN * atanf(rw / (rh + FEPS));
    const float rcf2 = cfr * SQL2E;

    __syncthreads();

    float sum = 0.f, a0 = 0.f, a1 = 0.f, a2 = 0.f, a3 = 0.f, a4 = 0.f;
    const float ONEP = 1.f + FEPS;

    // Software-pipelined j-loop: prefetch next record before computing current.
    float4 A = jrec[0], B = jrec[1], C = jrec[2];
#pragma unroll 4
    for (int jj = 0; jj < CH; jj++) {
        const int nx = ((jj + 1) & (CH - 1)) * 3;   // wrap: harmless extra load
        float4 nA = jrec[nx + 0];
        float4 nB = jrec[nx + 1];
        float4 nC = jrec[nx + 2];

        float iwr = fminf(rx2, A.z) - fmaxf(rx1, A.x);
        float ihr = fminf(ry2, A.w) - fmaxf(ry1, A.y);
        float iw = fmaxf(iwr, 0.f);
        float ih = fmaxf(ihr, 0.f);
        float inter = iw * ih;
        float uni = (rareps + C.x) - inter;
        float cw = (rw + B.z) - iwr;             // enclosing box identity
        float chh = (rh + B.w) - ihr;
        float c2 = fmaf(cw, cw, fmaf(chh, chh, FEPS));
        float dx = B.x - rhx;
        float dy = B.y - rhy;
        float rho2 = fmaf(dx, dx, dy * dy);      // /4 pre-folded
        float da = C.y - rat;                    // 4/pi^2 pre-folded
        float v = da * da;
        // P = den*uni, den = v - iou + 1 + eps  (den >= eps -> P >= eps*uni)
        float P = fmaf(v + ONEP, uni, -inter);
        P = fmaxf(P, 1e-12f);                    // fp-cancellation guard
        float uc = uni * c2;
        float rr = __builtin_amdgcn_rcpf(uc * P);   // ONE rcp per pair
        // numerator, independent of rr (overlaps rcp latency):
        float t1 = fmaf(inter, c2, -(rho2 * uni));
        float vu = v * uni;
        float n2 = (vu * vu) * c2;
        float num = fmaf(t1, P, -n2);
        float s = (num * rr) * (rcf2 * C.z);     // ciou * cf_i * cf_j * log2e
        float e = __builtin_amdgcn_exp2f(s);
        sum += e;
        a0 = fmaf(e, C.w, a0);
        a1 = fmaf(e, A.x, a1);
        a2 = fmaf(e, A.y, a2);
        a3 = fmaf(e, A.z, a3);
        a4 = fmaf(e, A.w, a4);

        A = nA; B = nB; C = nC;
    }

    float* p = part + (size_t)jt * N6 + (size_t)i * 6;
    p[0] = sum; p[1] = a0; p[2] = a1; p[3] = a2; p[4] = a3; p[5] = a4;
}

// One thread per output element (i,c): sum JT partials, softmax-divide, sigmoid.
// Unchanged from r0 (isolating the main-kernel change).
__global__ void epilogue_kernel(const float* __restrict__ x,
                                const float* __restrict__ gamma,
                                const float* __restrict__ part,
                                float* __restrict__ out) {
    int idx = blockIdx.x * blockDim.x + threadIdx.x;
    if (idx >= N * 5) return;
    int i = idx / 5, c = idx % 5;
    float se = 0.f, a = 0.f;
    const float* p = part + (size_t)i * 6;
#pragma unroll 8
    for (int jt = 0; jt < JT; jt++) {
        se += p[jt * (size_t)N6 + 0];
        a  += p[jt * (size_t)N6 + 1 + c];
    }
    float xp = x[idx] * gamma[0] + a / se;
    out[idx] = 1.f / (1.f + expf(-xp));
}

extern "C" void kernel_launch(void* const* d_in, const int* in_sizes, int n_in,
                              void* d_out, int out_size, void* d_ws, size_t ws_size,
                              hipStream_t stream) {
    const float* x = (const float*)d_in[0];
    const float* gamma = (const float*)d_in[1];
    float* out = (float*)d_out;
    float* part = (float*)d_ws;  // JT*N*6 floats = 6.29 MB

    ciou_attn_kernel<<<(N / BLK) * JT, BLK, 0, stream>>>(x, part);
    epilogue_kernel<<<(N * 5 + 255) / 256, 256, 0, stream>>>(x, gamma, part, out);
}